// Round 1
// baseline (444.748 us; speedup 1.0000x reference)
//
#include <hip/hip_runtime.h>

// ForwardBackwardImputer == pure forward-fill (backward pass is provably a
// no-op; see prior session analysis):
//   out[b,l,:] = x[b, F(b,l), :],  F(b,l) = cummax_{l'<=l}( valid(l') ? l' : 0 )
//   valid(l) <=> NOT all |x[b,l,d]| <= 1e-6
//
// Segment-local design: one block per 128-row segment resolves validity,
// copy-through, and in-segment fills (cache-hot). A tiny spine scan + head
// fix-up handles fills that cross segment boundaries (expected ~450 rows of
// 524288 total).

constexpr int Bn   = 256;
constexpr int Ln   = 2048;
constexpr int SEG  = 128;            // rows per block (64 KB of data)
constexpr int NSEG = Ln / SEG;       // 16 segments per batch
constexpr float A_TOL = 1e-6f;

// ---------------------------------------------------------------------------
// Main kernel: grid = Bn*NSEG blocks, 256 threads (32 lanes per row, 8 rows
// per iteration). Pass 1: load + validity + copy-through valid rows.
// Pass 2: fill missing rows that have an in-segment predecessor (bitmask MSB
// search; source row is L1/L2-hot). Head rows (no in-segment predecessor) are
// left for k_fix. Writes per-segment aggregates.
// ---------------------------------------------------------------------------
__global__ __launch_bounds__(256) void
k_main(const float* __restrict__ x, float* __restrict__ out,
       int* __restrict__ agg_first, int* __restrict__ agg_last) {
    const int sid    = blockIdx.x;
    const int b      = sid >> 4;               // NSEG = 16
    const int l0     = (sid & (NSEG - 1)) * SEG;
    const int tid    = threadIdx.x;
    const int lane32 = tid & 31;
    const int half   = (tid >> 5) & 1;         // which half of the wave64
    const int rgrp   = tid >> 5;               // row group 0..7

    __shared__ int sval[SEG];
    __shared__ unsigned long long sw[2];

    const float4* __restrict__ x4 = (const float4*)x;
    float4* __restrict__ o4       = (float4*)out;
    const size_t rowbase = (size_t)b * Ln + l0;   // global row index of row 0

    // ---- pass 1: load, validity, copy-through ----
    #pragma unroll
    for (int it = 0; it < SEG / 8; ++it) {
        const int    r   = it * 8 + rgrp;
        const size_t off = (rowbase + r) * 32 + lane32;   // float4 units
        const float4 v   = x4[off];
        const bool near0 = (__builtin_fabsf(v.x) <= A_TOL) &
                           (__builtin_fabsf(v.y) <= A_TOL) &
                           (__builtin_fabsf(v.z) <= A_TOL) &
                           (__builtin_fabsf(v.w) <= A_TOL);
        const unsigned long long bal = __ballot(near0);
        const unsigned mine = (unsigned)(bal >> (half * 32));
        const bool missing  = (mine == 0xffffffffu);   // all 128 features ~0
        if (!missing) o4[off] = v;
        if (lane32 == 0) sval[r] = missing ? 0 : 1;
    }
    __syncthreads();

    // ---- build 128-bit validity mask (wave 0 only) ----
    if (tid < 64) {
        const unsigned long long b0 = __ballot(sval[tid] != 0);
        const unsigned long long b1 = __ballot(sval[64 + tid] != 0);
        if (tid == 0) { sw[0] = b0; sw[1] = b1; }
    }
    __syncthreads();
    const unsigned long long m0 = sw[0], m1 = sw[1];

    // ---- pass 2: fill missing rows with in-segment predecessor ----
    #pragma unroll
    for (int it = 0; it < SEG / 8; ++it) {
        const int r = it * 8 + rgrp;
        if (sval[r]) continue;                 // valid: already written
        int F = -1;                            // last valid local idx <= r
        if (r >= 64) {
            unsigned long long m = m1 & ((r == 127) ? ~0ull
                                                    : ((1ull << (r - 63)) - 1ull));
            if (m)       F = 64 + 63 - __builtin_clzll(m);
            else if (m0) F = 63 - __builtin_clzll(m0);
        } else {
            unsigned long long m = m0 & ((r == 63) ? ~0ull
                                                   : ((1ull << (r + 1)) - 1ull));
            if (m) F = 63 - __builtin_clzll(m);
        }
        if (F < 0) continue;                   // head row -> k_fix
        const float4 s = x4[(rowbase + F) * 32 + lane32];   // L1/L2 hit
        o4[(rowbase + r) * 32 + lane32] = s;
    }

    // ---- per-segment aggregates ----
    if (tid == 0) {
        const int first = m0 ? __builtin_ctzll(m0)
                             : (m1 ? 64 + __builtin_ctzll(m1) : SEG);
        const int last  = m1 ? 127 - __builtin_clzll(m1)
                             : (m0 ? 63 - __builtin_clzll(m0) : -1);
        agg_first[sid] = first;                          // local idx of first valid (SEG if none)
        agg_last[sid]  = (last >= 0) ? (l0 + last) : -1; // batch-local l of last valid
    }
}

// ---------------------------------------------------------------------------
// Spine: exclusive running-max of last-valid over segments, per batch.
// One block, one thread per batch (16 serial steps each). ~4096 ints total.
// ---------------------------------------------------------------------------
__global__ __launch_bounds__(256) void
k_spine(const int* __restrict__ agg_last, int* __restrict__ carry) {
    const int b = threadIdx.x;                 // grid = 1 block of 256
    int c = 0;                                 // F before the batch = 0
    #pragma unroll
    for (int s = 0; s < NSEG; ++s) {
        const int sid = b * NSEG + s;
        carry[sid] = c;
        c = max(c, agg_last[sid]);             // -1 sentinel keeps c
    }
}

// ---------------------------------------------------------------------------
// Head fix-up: segments whose leading rows are all-missing get filled from
// the carry row. ~90% of blocks early-return after one scalar load.
// ---------------------------------------------------------------------------
__global__ __launch_bounds__(256) void
k_fix(const float* __restrict__ x, float* __restrict__ out,
      const int* __restrict__ agg_first, const int* __restrict__ carry) {
    const int sid   = blockIdx.x;
    const int first = agg_first[sid];
    if (first == 0) return;                    // row 0 valid: nothing to do
    const int b      = sid >> 4;
    const int l0     = (sid & (NSEG - 1)) * SEG;
    const int lane32 = threadIdx.x & 31;
    const int c      = carry[sid];             // batch-local source row
    const float4 s = ((const float4*)x)[((size_t)b * Ln + c) * 32 + lane32];
    float4* o4 = (float4*)out;
    for (int r = threadIdx.x >> 5; r < first; r += 8)
        o4[((size_t)b * Ln + l0 + r) * 32 + lane32] = s;
}

extern "C" void kernel_launch(void* const* d_in, const int* in_sizes, int n_in,
                              void* d_out, int out_size, void* d_ws, size_t ws_size,
                              hipStream_t stream) {
    const float* x = (const float*)d_in[0];
    float* out     = (float*)d_out;

    int* agg_first = (int*)d_ws;                   // Bn*NSEG = 4096 ints
    int* agg_last  = agg_first + Bn * NSEG;        // 4096 ints
    int* carry     = agg_last  + Bn * NSEG;        // 4096 ints  (48 KB total)

    const int nseg = Bn * NSEG;                    // 4096 blocks
    k_main <<<nseg, 256, 0, stream>>>(x, out, agg_first, agg_last);
    k_spine<<<1,    256, 0, stream>>>(agg_last, carry);
    k_fix  <<<nseg, 256, 0, stream>>>(x, out, agg_first, carry);
}